// Round 1
// 173.384 us; speedup vs baseline: 1.0271x; 1.0271x over previous
//
#include <hip/hip_runtime.h>
#include <math.h>

#define EDIM   1024
#define KVEDIM 256
#define HDIM   64
#define QHEADS 16

typedef __attribute__((ext_vector_type(8))) short short8;   // 8 bf16 (4 VGPRs)
typedef __attribute__((ext_vector_type(4))) float f32x4;

// fp32 -> bf16 (RNE)
__device__ __forceinline__ unsigned pack2(float a, float b) {
    unsigned ua = __builtin_bit_cast(unsigned, a);
    unsigned ub = __builtin_bit_cast(unsigned, b);
    ua += 0x7fffu + ((ua >> 16) & 1u);
    ub += 0x7fffu + ((ub >> 16) & 1u);
    return (ua >> 16) | (ub & 0xffff0000u);
}
__device__ __forceinline__ short f2b(float a) {
    unsigned ua = __builtin_bit_cast(unsigned, a);
    ua += 0x7fffu + ((ua >> 16) & 1u);
    return (short)(ua >> 16);
}
// packed RNE f32->bf16 pair in one instruction (same rounding as pack2)
__device__ __forceinline__ unsigned cvtpk(float a, float b) {
    unsigned r;
    asm("v_cvt_pk_bf16_f32 %0, %1, %2" : "=v"(r) : "v"(a), "v"(b));
    return r;
}

// ---------------------------------------------------------------------------
// Bulk fp32 -> bf16 conversion. grid = (1024, 6); 8 elems/thread.
// ---------------------------------------------------------------------------
__global__ __launch_bounds__(256)
void cvt_bf16(const float* __restrict__ s0, const float* __restrict__ s1,
              const float* __restrict__ s2, const float* __restrict__ s3,
              const float* __restrict__ s4, const float* __restrict__ s5,
              short* __restrict__ d0, short* __restrict__ d1,
              short* __restrict__ d2, short* __restrict__ d3,
              short* __restrict__ d4, short* __restrict__ d5,
              int n0, int n1, int n2, int n3, int n4, int n5)
{
    const float* s; short* d; int n;
    switch (blockIdx.y) {
        case 0: s = s0; d = d0; n = n0; break;
        case 1: s = s1; d = d1; n = n1; break;
        case 2: s = s2; d = d2; n = n2; break;
        case 3: s = s3; d = d3; n = n3; break;
        case 4: s = s4; d = d4; n = n4; break;
        default: s = s5; d = d5; n = n5; break;
    }
    int i = ((int)blockIdx.x * 256 + threadIdx.x) * 8;
    if (i >= n) return;
    float4 a = *(const float4*)&s[i];
    float4 b = *(const float4*)&s[i + 4];
    uint4 o;
    o.x = pack2(a.x, a.y); o.y = pack2(a.z, a.w);
    o.z = pack2(b.x, b.y); o.w = pack2(b.z, b.w);
    *(uint4*)&d[i] = o;
}

// ---------------------------------------------------------------------------
// bf16 projection GEMM: C[M,N] = (A[M,K] @ W[N,K]^T + bias) * scale (bf16 out)
// 128x128 tile, BK=64, 256 threads; wave computes 64x64 via 4x4 MFMA tiles.
// 1D grid decode: [0,128) = q, [128,160) = k, [160,192) = v.
// ---------------------------------------------------------------------------
__global__ __launch_bounds__(256)
void proj_gemm(const short* __restrict__ Aq, const short* __restrict__ Ak,
               const short* __restrict__ Av,
               const short* __restrict__ Wqb, const short* __restrict__ Wkb,
               const short* __restrict__ Wvb,
               const float* __restrict__ bq, const float* __restrict__ bk,
               const float* __restrict__ bv,
               short* __restrict__ Cq, short* __restrict__ Ck,
               short* __restrict__ Cv, float qscale)
{
    const int bid = blockIdx.x;
    const short* A; const short* W; const float* bias; short* C;
    int N, bm, bn; float scale;
    if (bid < 128) {
        A = Aq; W = Wqb; bias = bq; C = Cq; N = EDIM; scale = qscale;
        bm = (bid >> 3) * 128; bn = (bid & 7) * 128;
    } else if (bid < 160) {
        int i = bid - 128;
        A = Ak; W = Wkb; bias = bk; C = Ck; N = KVEDIM; scale = 1.0f;
        bm = (i >> 1) * 128; bn = (i & 1) * 128;
    } else {
        int i = bid - 160;
        A = Av; W = Wvb; bias = bv; C = Cv; N = KVEDIM; scale = 1.0f;
        bm = (i >> 1) * 128; bn = (i & 1) * 128;
    }
    const int K = EDIM;

    __shared__ short As[128 * 72];
    __shared__ short Ws[128 * 72];

    const int t = threadIdx.x, lane = t & 63, wv = t >> 6;
    const int lm = lane & 15, quad = lane >> 4;
    const int q8 = quad * 8, q4 = quad * 4;
    const int wm = (wv & 1) * 64, wn = (wv >> 1) * 64;
    const int sr = t >> 3, sc = (t & 7) * 8;   // staging: 32 rows/pass, 4 passes

    f32x4 zero = {0.f, 0.f, 0.f, 0.f};
    f32x4 acc[4][4];
    #pragma unroll
    for (int i = 0; i < 4; ++i)
        #pragma unroll
        for (int j = 0; j < 4; ++j) acc[i][j] = zero;

    for (int k0 = 0; k0 < K; k0 += 64) {
        __syncthreads();
        #pragma unroll
        for (int i = 0; i < 4; ++i) {
            int r = sr + i * 32;
            *(uint4*)&As[r * 72 + sc] = *(const uint4*)&A[(size_t)(bm + r) * K + k0 + sc];
            *(uint4*)&Ws[r * 72 + sc] = *(const uint4*)&W[(size_t)(bn + r) * K + k0 + sc];
        }
        __syncthreads();
        #pragma unroll
        for (int ks = 0; ks < 2; ++ks) {
            short8 af[4], bfr[4];
            #pragma unroll
            for (int i = 0; i < 4; ++i)
                af[i] = *(const short8*)&As[(wm + i * 16 + lm) * 72 + ks * 32 + q8];
            #pragma unroll
            for (int j = 0; j < 4; ++j)
                bfr[j] = *(const short8*)&Ws[(wn + j * 16 + lm) * 72 + ks * 32 + q8];
            #pragma unroll
            for (int i = 0; i < 4; ++i)
                #pragma unroll
                for (int j = 0; j < 4; ++j)
                    acc[i][j] = __builtin_amdgcn_mfma_f32_16x16x32_bf16(
                        af[i], bfr[j], acc[i][j], 0, 0, 0);
        }
    }

    #pragma unroll
    for (int j = 0; j < 4; ++j) {
        float bj = bias[bn + wn + j * 16 + lm];
        #pragma unroll
        for (int i = 0; i < 4; ++i)
            #pragma unroll
            for (int r = 0; r < 4; ++r)
                C[(size_t)(bm + wm + i * 16 + q4 + r) * N + bn + wn + j * 16 + lm] =
                    f2b((acc[i][j][r] + bj) * scale);
    }
}

// ---------------------------------------------------------------------------
// MFMA flash attention, split-KV. Block = 64 q-rows x 1 q-head, 4 waves;
// blockIdx.z selects a contiguous key range of s_len keys. The no-max exp2
// softmax is fully associative, so each split writes UNNORMALIZED fp32 O
// partials + per-row l partials; ln_kernel combines and normalizes.
// QK^T operand-SWAPPED (S' = K·Q^T); V transposed in staging via v_perm_b32;
// P packed with v_cvt_pk_bf16_f32.
// ---------------------------------------------------------------------------
__global__ __launch_bounds__(256)
void attn_mfma(const short* __restrict__ q, const short* __restrict__ k,
               const short* __restrict__ v, float* __restrict__ x,
               float* __restrict__ opart, float* __restrict__ lpart,
               int n, int s_len, int partial)
{
    __shared__ short Ks[64 * 72];   // K chunk [s][d]
    __shared__ short Vt[64 * 72];   // V chunk transposed [d][s]
    __shared__ short Ps[64 * 72];   // P [qrow][s]
    __shared__ float Lred[4][64];   // per-wave partial softmax denominators

    const int qh = blockIdx.y, kvh = qh >> 2;
    const int r0 = blockIdx.x * 64;
    const int t = threadIdx.x;
    const int lane = t & 63, wv = t >> 6;
    const int lm = lane & 15, quad = lane >> 4;
    const int q8 = quad * 8, q4 = quad * 4;

    // Q B-fragments for ALL 64 q-rows of this block (reused every chunk)
    short8 qf[4][2];
    #pragma unroll
    for (int qt = 0; qt < 4; ++qt) {
        const short* qrow = &q[(size_t)(r0 + qt * 16 + lm) * EDIM + qh * HDIM];
        qf[qt][0] = *(const short8*)&qrow[q8];
        qf[qt][1] = *(const short8*)&qrow[32 + q8];
    }

    const int rt0 = (wv & 1) * 2;    // PV row-tile base (q rows)
    const int dt0 = (wv >> 1) * 2;   // PV col-tile base (d)

    f32x4 zero = {0.f, 0.f, 0.f, 0.f};
    f32x4 oacc[2][2];
    #pragma unroll
    for (int i = 0; i < 2; ++i)
        #pragma unroll
        for (int j = 0; j < 2; ++j) oacc[i][j] = zero;
    float lp[4] = {0.f, 0.f, 0.f, 0.f};

    // staging maps
    const int krow = t >> 2, kc = (t & 3) * 8;          // K: 2x16B per thread
    const int vs4 = (t & 15) * 4, vd0 = (t >> 4) * 4;   // V transpose

    const int s_lo = (int)blockIdx.z * s_len;
    for (int s0 = s_lo; s0 < s_lo + s_len; s0 += 64) {
        __syncthreads();
        // ---- stage K chunk ----
        {
            const uint4* ksrc = (const uint4*)&k[(size_t)(s0 + krow) * KVEDIM + kvh * HDIM];
            uint4 ka = ksrc[t & 3];
            uint4 kb = ksrc[(t & 3) + 4];
            *(uint4*)&Ks[krow * 72 + kc] = ka;
            *(uint4*)&Ks[krow * 72 + kc + 32] = kb;
        }
        // ---- stage V transposed (byte-select transpose: 2 v_perm per d) ----
        {
            unsigned vr[4][2];
            #pragma unroll
            for (int i = 0; i < 4; ++i) {
                uint2 vv = *(const uint2*)&v[(size_t)(s0 + vs4 + i) * KVEDIM + kvh * HDIM + vd0];
                vr[i][0] = vv.x; vr[i][1] = vv.y;
            }
            #pragma unroll
            for (int j = 0; j < 4; ++j) {
                const unsigned sel = (j & 1) ? 0x07060302u : 0x05040100u;
                const int w = j >> 1;
                uint2 o;
                o.x = __builtin_amdgcn_perm(vr[1][w], vr[0][w], sel);
                o.y = __builtin_amdgcn_perm(vr[3][w], vr[2][w], sel);
                *(uint2*)&Vt[(vd0 + j) * 72 + vs4] = o;
            }
        }
        __syncthreads();

        // ---- S' = K_wv · Q^T : this wave's 16 keys x all 64 q-rows ----
        short8 kf0 = *(const short8*)&Ks[(wv * 16 + lm) * 72 + q8];
        short8 kf1 = *(const short8*)&Ks[(wv * 16 + lm) * 72 + 32 + q8];
        #pragma unroll
        for (int qt = 0; qt < 4; ++qt) {
            f32x4 s = zero;
            s = __builtin_amdgcn_mfma_f32_16x16x32_bf16(kf0, qf[qt][0], s, 0, 0, 0);
            s = __builtin_amdgcn_mfma_f32_16x16x32_bf16(kf1, qf[qt][1], s, 0, 0, 0);
            // lane holds keys wv*16+q4+0..3 for q-row qt*16+lm
            float p0 = exp2f(s[0]);
            float p1 = exp2f(s[1]);
            float p2 = exp2f(s[2]);
            float p3 = exp2f(s[3]);
            lp[qt] += (p0 + p1) + (p2 + p3);
            uint2 pw; pw.x = cvtpk(p0, p1); pw.y = cvtpk(p2, p3);
            *(uint2*)&Ps[(qt * 16 + lm) * 72 + wv * 16 + q4] = pw;
        }
        __syncthreads();

        // ---- O += P · V on this wave's 2x2 tile block ----
        short8 vf[2][2];
        #pragma unroll
        for (int j = 0; j < 2; ++j) {
            vf[j][0] = *(const short8*)&Vt[((dt0 + j) * 16 + lm) * 72 + q8];
            vf[j][1] = *(const short8*)&Vt[((dt0 + j) * 16 + lm) * 72 + 32 + q8];
        }
        #pragma unroll
        for (int i = 0; i < 2; ++i) {
            short8 pf0 = *(const short8*)&Ps[((rt0 + i) * 16 + lm) * 72 + q8];
            short8 pf1 = *(const short8*)&Ps[((rt0 + i) * 16 + lm) * 72 + 32 + q8];
            #pragma unroll
            for (int j = 0; j < 2; ++j) {
                oacc[i][j] = __builtin_amdgcn_mfma_f32_16x16x32_bf16(pf0, vf[j][0], oacc[i][j], 0, 0, 0);
                oacc[i][j] = __builtin_amdgcn_mfma_f32_16x16x32_bf16(pf1, vf[j][1], oacc[i][j], 0, 0, 0);
            }
        }
    }

    // ---- softmax denominator: quad-reduce then cross-wave via LDS ----
    #pragma unroll
    for (int qt = 0; qt < 4; ++qt) {
        float l = lp[qt];
        l += __shfl_xor(l, 16);
        l += __shfl_xor(l, 32);
        if (lane < 16) Lred[wv][qt * 16 + lm] = l;
    }
    __syncthreads();

    // ---- epilogue ----
    if (partial) {
        float* xp = opart + (size_t)blockIdx.z * n * EDIM;
        #pragma unroll
        for (int i = 0; i < 2; ++i) {
            #pragma unroll
            for (int r = 0; r < 4; ++r) {
                int row = (rt0 + i) * 16 + q4 + r;
                float lsum = (Lred[0][row] + Lred[1][row]) + (Lred[2][row] + Lred[3][row]);
                if (dt0 == 0 && lm == 0)
                    lpart[(size_t)blockIdx.z * n * QHEADS + (size_t)(r0 + row) * QHEADS + qh] = lsum;
                #pragma unroll
                for (int j = 0; j < 2; ++j)
                    xp[(size_t)(r0 + row) * EDIM + qh * HDIM + (dt0 + j) * 16 + lm] =
                        oacc[i][j][r];
            }
        }
    } else {
        #pragma unroll
        for (int i = 0; i < 2; ++i) {
            #pragma unroll
            for (int r = 0; r < 4; ++r) {
                int row = (rt0 + i) * 16 + q4 + r;
                float lsum = (Lred[0][row] + Lred[1][row]) + (Lred[2][row] + Lred[3][row]);
                float inv = 1.0f / lsum;
                #pragma unroll
                for (int j = 0; j < 2; ++j)
                    x[(size_t)(r0 + row) * EDIM + qh * HDIM + (dt0 + j) * 16 + lm] =
                        oacc[i][j][r] * inv;
            }
        }
    }
}

// ---------------------------------------------------------------------------
// Split-KV combine (unnormalized O partials / l partials) + LayerNorm.
// nsplit == 0: plain in-place LN on x (fallback path).
// ---------------------------------------------------------------------------
__global__ __launch_bounds__(256)
void ln_kernel(float* __restrict__ x, const float* __restrict__ gamma,
               const float* __restrict__ beta,
               const float* __restrict__ opart, const float* __restrict__ lpart,
               int nsplit, int n)
{
    const int row = blockIdx.x;
    const int t = threadIdx.x;

    float4 xv;
    if (nsplit > 0) {
        const int head = t >> 4;                 // (t*4)/64
        float l = 0.f;
        float4 s = {0.f, 0.f, 0.f, 0.f};
        for (int z = 0; z < nsplit; ++z) {
            const float4 o = *(const float4*)&opart[(size_t)z * n * EDIM +
                                                    (size_t)row * EDIM + t * 4];
            s.x += o.x; s.y += o.y; s.z += o.z; s.w += o.w;
            l += lpart[(size_t)z * n * QHEADS + (size_t)row * QHEADS + head];
        }
        const float inv = 1.f / l;
        xv.x = s.x * inv; xv.y = s.y * inv; xv.z = s.z * inv; xv.w = s.w * inv;
    } else {
        xv = *(const float4*)&x[(size_t)row * EDIM + t * 4];
    }

    float sm  = xv.x + xv.y + xv.z + xv.w;
    float sq = xv.x * xv.x + xv.y * xv.y + xv.z * xv.z + xv.w * xv.w;
    #pragma unroll
    for (int m = 1; m < 64; m <<= 1) {
        sm += __shfl_xor(sm, m);
        sq += __shfl_xor(sq, m);
    }
    __shared__ float ws_[4], wq_[4];
    const int wave = t >> 6;
    if ((t & 63) == 0) { ws_[wave] = sm; wq_[wave] = sq; }
    __syncthreads();
    sm = ws_[0] + ws_[1] + ws_[2] + ws_[3];
    sq = wq_[0] + wq_[1] + wq_[2] + wq_[3];

    const float mu   = sm * (1.f / EDIM);
    const float var  = sq * (1.f / EDIM) - mu * mu;
    const float rstd = rsqrtf(var + 1e-5f);

    float4 g = *(const float4*)&gamma[t * 4];
    float4 b = *(const float4*)&beta[t * 4];
    float4 o;
    o.x = (xv.x - mu) * rstd * g.x + b.x;
    o.y = (xv.y - mu) * rstd * g.y + b.y;
    o.z = (xv.z - mu) * rstd * g.z + b.z;
    o.w = (xv.w - mu) * rstd * g.w + b.w;
    *(float4*)&x[(size_t)row * EDIM + t * 4] = o;
}

// ---------------------------------------------------------------------------
extern "C" void kernel_launch(void* const* d_in, const int* in_sizes, int n_in,
                              void* d_out, int out_size, void* d_ws, size_t ws_size,
                              hipStream_t stream)
{
    const float* query = (const float*)d_in[0];
    const float* key   = (const float*)d_in[1];
    const float* value = (const float*)d_in[2];
    const float* Wq    = (const float*)d_in[3];
    const float* bq    = (const float*)d_in[4];
    const float* Wk    = (const float*)d_in[5];
    const float* bk    = (const float*)d_in[6];
    const float* Wv    = (const float*)d_in[7];
    const float* bv    = (const float*)d_in[8];
    const float* gamma = (const float*)d_in[9];
    const float* beta  = (const float*)d_in[10];
    float* out = (float*)d_out;

    const int n = in_sizes[0] / EDIM;   // 2048

    // workspace layout (bf16 shorts)
    short* qa  = (short*)d_ws;                 // query bf16  n*1024
    short* ka  = qa  + (size_t)n * EDIM;       // key   bf16  n*1024
    short* va  = ka  + (size_t)n * EDIM;       // value bf16  n*1024
    short* wqb = va  + (size_t)n * EDIM;       // Wq bf16 1024*1024
    short* wkb = wqb + (size_t)EDIM * EDIM;    // Wk bf16 256*1024
    short* wvb = wkb + (size_t)KVEDIM * EDIM;  // Wv bf16 256*1024
    short* qb  = wvb + (size_t)KVEDIM * EDIM;  // q proj  n*1024
    short* kb  = qb  + (size_t)n * EDIM;       // k proj  n*256
    short* vb  = kb  + (size_t)n * KVEDIM;     // v proj  n*256
    short* ws_end = vb + (size_t)n * KVEDIM;

    // split-KV partial buffers (fp32) after the bf16 region
    const size_t base_bytes = (size_t)((char*)ws_end - (char*)d_ws);
    int nsplit = 0;
    for (int cand = 4; cand >= 1; cand >>= 1) {
        if (n % (64 * cand)) continue;
        size_t need = base_bytes +
                      (size_t)cand * ((size_t)n * EDIM + (size_t)n * QHEADS) * sizeof(float);
        if (need <= ws_size) { nsplit = cand; break; }
    }
    float* opart = (float*)ws_end;
    float* lpart = opart + (size_t)(nsplit > 0 ? nsplit : 1) * n * EDIM;

    // 1/sqrt(64) * log2(e): exp2-based softmax without max subtraction
    const float qscale = 0.125f * 1.44269504088896f;

    cvt_bf16<<<dim3(1024, 6), 256, 0, stream>>>(
        query, key, value, Wq, Wk, Wv,
        qa, ka, va, wqb, wkb, wvb,
        n * EDIM, n * EDIM, n * EDIM, EDIM * EDIM, KVEDIM * EDIM, KVEDIM * EDIM);

    proj_gemm<<<dim3(192), 256, 0, stream>>>(
        qa, ka, va, wqb, wkb, wvb, bq, bk, bv, qb, kb, vb, qscale);

    const int zdim  = (nsplit > 0) ? nsplit : 1;
    const int s_len = n / zdim;
    attn_mfma<<<dim3(n / 64, QHEADS, zdim), 256, 0, stream>>>(
        qb, kb, vb, out, opart, lpart, n, s_len, nsplit > 0 ? 1 : 0);

    ln_kernel<<<dim3(n), 256, 0, stream>>>(out, gamma, beta, opart, lpart, nsplit, n);
}

// Round 3
// 162.449 us; speedup vs baseline: 1.0963x; 1.0673x over previous
//
#include <hip/hip_runtime.h>
#include <math.h>

#define EDIM   1024
#define KVEDIM 256
#define HDIM   64
#define QHEADS 16

typedef __attribute__((ext_vector_type(8))) short short8;   // 8 bf16 (4 VGPRs)
typedef __attribute__((ext_vector_type(4))) float f32x4;

// fp32 -> bf16 (RNE)
__device__ __forceinline__ unsigned pack2(float a, float b) {
    unsigned ua = __builtin_bit_cast(unsigned, a);
    unsigned ub = __builtin_bit_cast(unsigned, b);
    ua += 0x7fffu + ((ua >> 16) & 1u);
    ub += 0x7fffu + ((ub >> 16) & 1u);
    return (ua >> 16) | (ub & 0xffff0000u);
}
__device__ __forceinline__ short f2b(float a) {
    unsigned ua = __builtin_bit_cast(unsigned, a);
    ua += 0x7fffu + ((ua >> 16) & 1u);
    return (short)(ua >> 16);
}
// packed RNE f32->bf16 pair in one instruction (same rounding as pack2)
__device__ __forceinline__ unsigned cvtpk(float a, float b) {
    unsigned r;
    asm("v_cvt_pk_bf16_f32 %0, %1, %2" : "=v"(r) : "v"(a), "v"(b));
    return r;
}

// ---------------------------------------------------------------------------
// Bulk fp32 -> bf16 conversion. grid = (1024, 6); 8 elems/thread.
// ---------------------------------------------------------------------------
__global__ __launch_bounds__(256)
void cvt_bf16(const float* __restrict__ s0, const float* __restrict__ s1,
              const float* __restrict__ s2, const float* __restrict__ s3,
              const float* __restrict__ s4, const float* __restrict__ s5,
              short* __restrict__ d0, short* __restrict__ d1,
              short* __restrict__ d2, short* __restrict__ d3,
              short* __restrict__ d4, short* __restrict__ d5,
              int n0, int n1, int n2, int n3, int n4, int n5)
{
    const float* s; short* d; int n;
    switch (blockIdx.y) {
        case 0: s = s0; d = d0; n = n0; break;
        case 1: s = s1; d = d1; n = n1; break;
        case 2: s = s2; d = d2; n = n2; break;
        case 3: s = s3; d = d3; n = n3; break;
        case 4: s = s4; d = d4; n = n4; break;
        default: s = s5; d = d5; n = n5; break;
    }
    int i = ((int)blockIdx.x * 256 + threadIdx.x) * 8;
    if (i >= n) return;
    float4 a = *(const float4*)&s[i];
    float4 b = *(const float4*)&s[i + 4];
    uint4 o;
    o.x = pack2(a.x, a.y); o.y = pack2(a.z, a.w);
    o.z = pack2(b.x, b.y); o.w = pack2(b.z, b.w);
    *(uint4*)&d[i] = o;
}

// ---------------------------------------------------------------------------
// bf16 projection GEMM: C[M,N] = (A[M,K] @ W[N,K]^T + bias) * scale (bf16 out)
// 128x128 tile, BK=64, 256 threads; wave computes 64x64 via 4x4 MFMA tiles.
// 1D grid decode: [0,128) = q, [128,160) = k, [160,192) = v.
// ---------------------------------------------------------------------------
__global__ __launch_bounds__(256)
void proj_gemm(const short* __restrict__ Aq, const short* __restrict__ Ak,
               const short* __restrict__ Av,
               const short* __restrict__ Wqb, const short* __restrict__ Wkb,
               const short* __restrict__ Wvb,
               const float* __restrict__ bq, const float* __restrict__ bk,
               const float* __restrict__ bv,
               short* __restrict__ Cq, short* __restrict__ Ck,
               short* __restrict__ Cv, float qscale)
{
    const int bid = blockIdx.x;
    const short* A; const short* W; const float* bias; short* C;
    int N, bm, bn; float scale;
    if (bid < 128) {
        A = Aq; W = Wqb; bias = bq; C = Cq; N = EDIM; scale = qscale;
        bm = (bid >> 3) * 128; bn = (bid & 7) * 128;
    } else if (bid < 160) {
        int i = bid - 128;
        A = Ak; W = Wkb; bias = bk; C = Ck; N = KVEDIM; scale = 1.0f;
        bm = (i >> 1) * 128; bn = (i & 1) * 128;
    } else {
        int i = bid - 160;
        A = Av; W = Wvb; bias = bv; C = Cv; N = KVEDIM; scale = 1.0f;
        bm = (i >> 1) * 128; bn = (i & 1) * 128;
    }
    const int K = EDIM;

    __shared__ short As[128 * 72];
    __shared__ short Ws[128 * 72];

    const int t = threadIdx.x, lane = t & 63, wv = t >> 6;
    const int lm = lane & 15, quad = lane >> 4;
    const int q8 = quad * 8, q4 = quad * 4;
    const int wm = (wv & 1) * 64, wn = (wv >> 1) * 64;
    const int sr = t >> 3, sc = (t & 7) * 8;   // staging: 32 rows/pass, 4 passes

    f32x4 zero = {0.f, 0.f, 0.f, 0.f};
    f32x4 acc[4][4];
    #pragma unroll
    for (int i = 0; i < 4; ++i)
        #pragma unroll
        for (int j = 0; j < 4; ++j) acc[i][j] = zero;

    for (int k0 = 0; k0 < K; k0 += 64) {
        __syncthreads();
        #pragma unroll
        for (int i = 0; i < 4; ++i) {
            int r = sr + i * 32;
            *(uint4*)&As[r * 72 + sc] = *(const uint4*)&A[(size_t)(bm + r) * K + k0 + sc];
            *(uint4*)&Ws[r * 72 + sc] = *(const uint4*)&W[(size_t)(bn + r) * K + k0 + sc];
        }
        __syncthreads();
        #pragma unroll
        for (int ks = 0; ks < 2; ++ks) {
            short8 af[4], bfr[4];
            #pragma unroll
            for (int i = 0; i < 4; ++i)
                af[i] = *(const short8*)&As[(wm + i * 16 + lm) * 72 + ks * 32 + q8];
            #pragma unroll
            for (int j = 0; j < 4; ++j)
                bfr[j] = *(const short8*)&Ws[(wn + j * 16 + lm) * 72 + ks * 32 + q8];
            #pragma unroll
            for (int i = 0; i < 4; ++i)
                #pragma unroll
                for (int j = 0; j < 4; ++j)
                    acc[i][j] = __builtin_amdgcn_mfma_f32_16x16x32_bf16(
                        af[i], bfr[j], acc[i][j], 0, 0, 0);
        }
    }

    #pragma unroll
    for (int j = 0; j < 4; ++j) {
        float bj = bias[bn + wn + j * 16 + lm];
        #pragma unroll
        for (int i = 0; i < 4; ++i)
            #pragma unroll
            for (int r = 0; r < 4; ++r)
                C[(size_t)(bm + wm + i * 16 + q4 + r) * N + bn + wn + j * 16 + lm] =
                    f2b((acc[i][j][r] + bj) * scale);
    }
}

// ---------------------------------------------------------------------------
// MFMA flash attention. Block = 16 q-rows x 4 q-heads (one wave per q-head),
// sharing one KV head; blockIdx.z = KV split (associative no-max exp2
// softmax -> unnormalized partials combined in ln_kernel).
//
// QK^T operand-swapped (S' = K.Q^T): lane(lm,quad) reg r holds
// P[qrow=lm][key=kt*16+quad*4+r] == the A-fragment slot (quad, elem) of a
// bf16 MFMA. PV packs two 16-key tiles into ONE full-K mfma_f32_16x16x32:
//   A = {pa[2t].x, pa[2t].y, pa[2t+1].x, pa[2t+1].y}
// Pairing is layout-robust: A(quad,e) multiplies B(quad,e) regardless of the
// internal k-map, so V is staged element-matched:
//   Vs slot = dt*128 + ktp*64 + quad*16 + lm, elems half*4+j
//   (s = ktp*32 + half*16 + quad*4 + j, d = dt*16 + lm)
// Both Ks ([64][64], no pad) and Vs use the slot-XOR involution
//   slot ^= (slot>>4)&7   (16B slots)
// -> K write/read and V read bank-uniform (free), V write 2-way (free).
// P never touches LDS: 2 barriers/chunk, no cross-wave reductions.
// ---------------------------------------------------------------------------
__global__ __launch_bounds__(256, 4)
void attn_mfma(const short* __restrict__ q, const short* __restrict__ k,
               const short* __restrict__ v, float* __restrict__ x,
               float* __restrict__ opart, float* __restrict__ lpart,
               int n, int s_len, int partial)
{
    __shared__ short Ks[64 * 64];   // K chunk [s][d], slot-XOR swizzled (8 KB)
    __shared__ short Vs[4096];      // V chunk, PV-frag layout, swizzled (8 KB)

    const int kvh = blockIdx.y;
    const int r0  = blockIdx.x * 16;
    const int t = threadIdx.x, lane = t & 63, wv = t >> 6;
    const int qh = (kvh << 2) | wv;          // wave's q-head
    const int lm = lane & 15, quad = lane >> 4, q8 = quad * 8;

    // Q B-fragments for this wave's 16 q-rows (reused every chunk)
    short8 qf0, qf1;
    {
        const short* qp = &q[(size_t)(r0 + lm) * EDIM + qh * HDIM];
        qf0 = *(const short8*)&qp[q8];
        qf1 = *(const short8*)&qp[32 + q8];
    }

    const f32x4 zero = {0.f, 0.f, 0.f, 0.f};
    f32x4 oacc[4] = {zero, zero, zero, zero};   // O[qrow=quad*4+r][d=dt*16+lm]
    float lp = 0.f;

    // staging maps
    const int sr  = t >> 2;                  // K source row (0..63)
    const int scs = (t & 3) * 16;            // K col base (shorts)
    const int kw0 = sr * 64 + (scs ^ ((sr & 7) << 3));
    const int kw1 = sr * 64 + ((scs + 8) ^ ((sr & 7) << 3));
    const int vs4 = (t & 15) * 4;            // V: s-block
    const int vd0 = (t >> 4) * 4;            // V: d-block
    const int vktp = vs4 >> 5, vqd = (vs4 >> 2) & 3, vhf = (vs4 >> 4) & 1;

    // QK read column offsets (swizzled)
    const int krx  = q8 ^ ((lm & 7) << 3);
    const int krx2 = (32 + q8) ^ ((lm & 7) << 3);

    const int s_lo = (int)blockIdx.z * s_len;
    const int s_hi = s_lo + s_len;
    const size_t kbase = (size_t)kvh * HDIM;

    // prefetch first chunk into registers
    uint4 kra, krb;
    uint2 vrr[4];
    {
        const uint4* ks = (const uint4*)&k[(size_t)(s_lo + sr) * KVEDIM + kbase + scs];
        kra = ks[0]; krb = ks[1];
        #pragma unroll
        for (int i = 0; i < 4; ++i)
            vrr[i] = *(const uint2*)&v[(size_t)(s_lo + vs4 + i) * KVEDIM + kbase + vd0];
    }

    for (int s0 = s_lo; s0 < s_hi; s0 += 64) {
        // ---- write staged registers to LDS ----
        *(uint4*)&Ks[kw0] = kra;
        *(uint4*)&Ks[kw1] = krb;
        #pragma unroll
        for (int j = 0; j < 4; ++j) {
            const unsigned sel = (j & 1) ? 0x07060302u : 0x05040100u;
            unsigned a0 = (j < 2) ? vrr[0].x : vrr[0].y;
            unsigned a1 = (j < 2) ? vrr[1].x : vrr[1].y;
            unsigned a2 = (j < 2) ? vrr[2].x : vrr[2].y;
            unsigned a3 = (j < 2) ? vrr[3].x : vrr[3].y;
            uint2 o;                          // (V[vs4..vs4+3][dd]) bf16 x4
            o.x = __builtin_amdgcn_perm(a1, a0, sel);
            o.y = __builtin_amdgcn_perm(a3, a2, sel);
            const int dd = vd0 + j;
            int slot = ((dd >> 4) << 7) + (vktp << 6) + (vqd << 4) + (dd & 15);
            slot ^= (slot >> 4) & 7;
            *(uint2*)&Vs[slot * 8 + vhf * 4] = o;
        }
        __syncthreads();

        // ---- issue next chunk's global loads early (hide under compute) ----
        if (s0 + 64 < s_hi) {
            const uint4* ks = (const uint4*)&k[(size_t)(s0 + 64 + sr) * KVEDIM + kbase + scs];
            kra = ks[0]; krb = ks[1];
            #pragma unroll
            for (int i = 0; i < 4; ++i)
                vrr[i] = *(const uint2*)&v[(size_t)(s0 + 64 + vs4 + i) * KVEDIM + kbase + vd0];
        }

        // ---- S' = K . Q^T for this wave's head; P kept in registers ----
        uint2 pa[4];
        #pragma unroll
        for (int kt = 0; kt < 4; ++kt) {
            const int krow = (kt * 16 + lm) * 64;
            short8 kf0 = *(const short8*)&Ks[krow + krx];
            short8 kf1 = *(const short8*)&Ks[krow + krx2];
            f32x4 s = zero;
            s = __builtin_amdgcn_mfma_f32_16x16x32_bf16(kf0, qf0, s, 0, 0, 0);
            s = __builtin_amdgcn_mfma_f32_16x16x32_bf16(kf1, qf1, s, 0, 0, 0);
            float p0 = exp2f(s[0]), p1 = exp2f(s[1]);
            float p2 = exp2f(s[2]), p3 = exp2f(s[3]);
            lp += (p0 + p1) + (p2 + p3);
            pa[kt].x = cvtpk(p0, p1);        // keys quad*4+0,1 of tile kt
            pa[kt].y = cvtpk(p2, p3);        // keys quad*4+2,3 of tile kt
        }

        // ---- O += P . V : full-K=32 MFMAs, A packs two 16-key tiles ----
        uint4 ap0; ap0.x = pa[0].x; ap0.y = pa[0].y; ap0.z = pa[1].x; ap0.w = pa[1].y;
        uint4 ap1; ap1.x = pa[2].x; ap1.y = pa[2].y; ap1.z = pa[3].x; ap1.w = pa[3].y;
        #pragma unroll
        for (int dt = 0; dt < 4; ++dt) {
            int sb  = (dt << 7) + (quad << 4) + lm;       // ktp=0
            int sx0 = sb ^ ((sb >> 4) & 7);
            int sb1 = sb + 64;                            // ktp=1
            int sx1 = sb1 ^ ((sb1 >> 4) & 7);
            oacc[dt] = __builtin_amdgcn_mfma_f32_16x16x32_bf16(
                __builtin_bit_cast(short8, ap0),
                *(const short8*)&Vs[sx0 * 8], oacc[dt], 0, 0, 0);
            oacc[dt] = __builtin_amdgcn_mfma_f32_16x16x32_bf16(
                __builtin_bit_cast(short8, ap1),
                *(const short8*)&Vs[sx1 * 8], oacc[dt], 0, 0, 0);
        }
        __syncthreads();   // all waves done reading LDS before next overwrite
    }

    // ---- softmax denominator: reduce across quads (same lm = same qrow) ----
    float lt = lp;
    lt += __shfl_xor(lt, 16);
    lt += __shfl_xor(lt, 32);
    // every lane now holds the full l-sum for qrow = lm

    if (partial) {
        float* xp = opart + (size_t)blockIdx.z * n * EDIM;
        if (lane < 16)
            lpart[(size_t)blockIdx.z * n * QHEADS + (size_t)(r0 + lane) * QHEADS + qh] = lt;
        #pragma unroll
        for (int r = 0; r < 4; ++r) {
            const int row = r0 + quad * 4 + r;
            #pragma unroll
            for (int dt = 0; dt < 4; ++dt)
                xp[(size_t)row * EDIM + qh * HDIM + dt * 16 + lm] = oacc[dt][r];
        }
    } else {
        float linv[4];
        #pragma unroll
        for (int r = 0; r < 4; ++r)
            linv[r] = 1.0f / __shfl(lt, quad * 4 + r);
        #pragma unroll
        for (int r = 0; r < 4; ++r) {
            const int row = r0 + quad * 4 + r;
            #pragma unroll
            for (int dt = 0; dt < 4; ++dt)
                x[(size_t)row * EDIM + qh * HDIM + dt * 16 + lm] = oacc[dt][r] * linv[r];
        }
    }
}

// ---------------------------------------------------------------------------
// Split-KV combine (unnormalized O partials / l partials) + LayerNorm.
// nsplit == 0: plain in-place LN on x (fallback path).
// ---------------------------------------------------------------------------
__global__ __launch_bounds__(256)
void ln_kernel(float* __restrict__ x, const float* __restrict__ gamma,
               const float* __restrict__ beta,
               const float* __restrict__ opart, const float* __restrict__ lpart,
               int nsplit, int n)
{
    const int row = blockIdx.x;
    const int t = threadIdx.x;

    float4 xv;
    if (nsplit > 0) {
        const int head = t >> 4;                 // (t*4)/64
        float l = 0.f;
        float4 s = {0.f, 0.f, 0.f, 0.f};
        for (int z = 0; z < nsplit; ++z) {
            const float4 o = *(const float4*)&opart[(size_t)z * n * EDIM +
                                                    (size_t)row * EDIM + t * 4];
            s.x += o.x; s.y += o.y; s.z += o.z; s.w += o.w;
            l += lpart[(size_t)z * n * QHEADS + (size_t)row * QHEADS + head];
        }
        const float inv = 1.f / l;
        xv.x = s.x * inv; xv.y = s.y * inv; xv.z = s.z * inv; xv.w = s.w * inv;
    } else {
        xv = *(const float4*)&x[(size_t)row * EDIM + t * 4];
    }

    float sm  = xv.x + xv.y + xv.z + xv.w;
    float sq = xv.x * xv.x + xv.y * xv.y + xv.z * xv.z + xv.w * xv.w;
    #pragma unroll
    for (int m = 1; m < 64; m <<= 1) {
        sm += __shfl_xor(sm, m);
        sq += __shfl_xor(sq, m);
    }
    __shared__ float ws_[4], wq_[4];
    const int wave = t >> 6;
    if ((t & 63) == 0) { ws_[wave] = sm; wq_[wave] = sq; }
    __syncthreads();
    sm = ws_[0] + ws_[1] + ws_[2] + ws_[3];
    sq = wq_[0] + wq_[1] + wq_[2] + wq_[3];

    const float mu   = sm * (1.f / EDIM);
    const float var  = sq * (1.f / EDIM) - mu * mu;
    const float rstd = rsqrtf(var + 1e-5f);

    float4 g = *(const float4*)&gamma[t * 4];
    float4 b = *(const float4*)&beta[t * 4];
    float4 o;
    o.x = (xv.x - mu) * rstd * g.x + b.x;
    o.y = (xv.y - mu) * rstd * g.y + b.y;
    o.z = (xv.z - mu) * rstd * g.z + b.z;
    o.w = (xv.w - mu) * rstd * g.w + b.w;
    *(float4*)&x[(size_t)row * EDIM + t * 4] = o;
}

// ---------------------------------------------------------------------------
extern "C" void kernel_launch(void* const* d_in, const int* in_sizes, int n_in,
                              void* d_out, int out_size, void* d_ws, size_t ws_size,
                              hipStream_t stream)
{
    const float* query = (const float*)d_in[0];
    const float* key   = (const float*)d_in[1];
    const float* value = (const float*)d_in[2];
    const float* Wq    = (const float*)d_in[3];
    const float* bq    = (const float*)d_in[4];
    const float* Wk    = (const float*)d_in[5];
    const float* bk    = (const float*)d_in[6];
    const float* Wv    = (const float*)d_in[7];
    const float* bv    = (const float*)d_in[8];
    const float* gamma = (const float*)d_in[9];
    const float* beta  = (const float*)d_in[10];
    float* out = (float*)d_out;

    const int n = in_sizes[0] / EDIM;   // 2048

    // workspace layout (bf16 shorts)
    short* qa  = (short*)d_ws;                 // query bf16  n*1024
    short* ka  = qa  + (size_t)n * EDIM;       // key   bf16  n*1024
    short* va  = ka  + (size_t)n * EDIM;       // value bf16  n*1024
    short* wqb = va  + (size_t)n * EDIM;       // Wq bf16 1024*1024
    short* wkb = wqb + (size_t)EDIM * EDIM;    // Wk bf16 256*1024
    short* wvb = wkb + (size_t)KVEDIM * EDIM;  // Wv bf16 256*1024
    short* qb  = wvb + (size_t)KVEDIM * EDIM;  // q proj  n*1024
    short* kb  = qb  + (size_t)n * EDIM;       // k proj  n*256
    short* vb  = kb  + (size_t)n * KVEDIM;     // v proj  n*256
    short* ws_end = vb + (size_t)n * KVEDIM;

    // split-KV partial buffers (fp32) after the bf16 region
    const size_t base_bytes = (size_t)((char*)ws_end - (char*)d_ws);
    int nsplit = 0;
    {
        const int cand = 2;   // 1024 blocks = 4/CU (residency limit anyway)
        size_t need = base_bytes +
                      (size_t)cand * ((size_t)n * EDIM + (size_t)n * QHEADS) * sizeof(float);
        if ((n % (64 * cand)) == 0 && need <= ws_size) nsplit = cand;
    }
    float* opart = (float*)ws_end;
    float* lpart = opart + (size_t)(nsplit > 0 ? nsplit : 1) * n * EDIM;

    // 1/sqrt(64) * log2(e): exp2-based softmax without max subtraction
    const float qscale = 0.125f * 1.44269504088896f;

    cvt_bf16<<<dim3(1024, 6), 256, 0, stream>>>(
        query, key, value, Wq, Wk, Wv,
        qa, ka, va, wqb, wkb, wvb,
        n * EDIM, n * EDIM, n * EDIM, EDIM * EDIM, KVEDIM * EDIM, KVEDIM * EDIM);

    proj_gemm<<<dim3(192), 256, 0, stream>>>(
        qa, ka, va, wqb, wkb, wvb, bq, bk, bv, qb, kb, vb, qscale);

    const int zdim  = (nsplit > 0) ? nsplit : 1;
    const int s_len = n / zdim;
    attn_mfma<<<dim3(n / 16, 4, zdim), 256, 0, stream>>>(
        qb, kb, vb, out, opart, lpart, n, s_len, nsplit > 0 ? 1 : 0);

    ln_kernel<<<dim3(n), 256, 0, stream>>>(out, gamma, beta, opart, lpart, nsplit, n);
}